// Round 13
// baseline (255.580 us; speedup 1.0000x reference)
//
#include <hip/hip_runtime.h>
#include <hip/hip_bf16.h>

// Problem constants: B=2, C=512, H=W=64 -> N=4096, G=32 (16 ch/group), EPS=1e-6.

typedef float f32x4 __attribute__((ext_vector_type(4)));
typedef __bf16 bf16x8 __attribute__((ext_vector_type(8)));

typedef const __attribute__((address_space(1))) unsigned char* gas_p;
typedef __attribute__((address_space(3))) unsigned char* las_p;

__device__ __forceinline__ void gload_lds16(const void* g, void* l) {
  // async DMA: each lane contributes 16B; LDS dst = wave-uniform base + lane*16
  __builtin_amdgcn_global_load_lds((gas_p)g, (las_p)l, 16, 0, 0);
}

// ====== prelude: weight cvt (4x1024 blocks) | gn_stats (64) | bcat (1) ======
__global__ __launch_bounds__(256) void prelude_k(
    const float* __restrict__ wq, const float* __restrict__ wk,
    const float* __restrict__ wv, const float* __restrict__ wo,
    __hip_bfloat16* __restrict__ wqkb, __hip_bfloat16* __restrict__ wvb,
    __hip_bfloat16* __restrict__ wob, const float* __restrict__ bq,
    const float* __restrict__ bk, float* __restrict__ bqk,
    const float* __restrict__ x, float* __restrict__ stats) {
  int bid = blockIdx.x;
  if (bid < 4096) {
    const float* src;
    __hip_bfloat16* dst;
    if (bid < 1024)      { src = wq; dst = wqkb; }
    else if (bid < 2048) { src = wk; dst = wqkb + 262144; }
    else if (bid < 3072) { src = wv; dst = wvb; }
    else                 { src = wo; dst = wob; }
    int i = (bid & 1023) * 256 + threadIdx.x;  // 1024*256 = 262144 = 512*512
    dst[i] = __float2bfloat16(src[i]);
    return;
  }
  if (bid < 4160) {  // gn_stats: one block per (b,g)
    int bg = bid - 4096;
    const float4* p = (const float4*)(x + (size_t)bg * 65536);
    float s = 0.f, s2 = 0.f;
    for (int i = threadIdx.x; i < 16384; i += 256) {
      float4 v = p[i];
      s  += v.x + v.y + v.z + v.w;
      s2 += v.x * v.x + v.y * v.y + v.z * v.z + v.w * v.w;
    }
#pragma unroll
    for (int off = 32; off > 0; off >>= 1) {
      s  += __shfl_xor(s, off);
      s2 += __shfl_xor(s2, off);
    }
    __shared__ float rs[4], rs2[4];
    int wid = threadIdx.x >> 6, lane = threadIdx.x & 63;
    if (lane == 0) { rs[wid] = s; rs2[wid] = s2; }
    __syncthreads();
    if (threadIdx.x == 0) {
      float S  = rs[0] + rs[1] + rs[2] + rs[3];
      float S2 = rs2[0] + rs2[1] + rs2[2] + rs2[3];
      float mean = S * (1.f / 65536.f);
      float var  = S2 * (1.f / 65536.f) - mean * mean;
      stats[bg * 2]     = mean;
      stats[bg * 2 + 1] = rsqrtf(var + 1e-6f);
    }
    return;
  }
  // bcat
  for (int j = threadIdx.x; j < 1024; j += 256)
    bqk[j] = (j < 512) ? bq[j] : bk[j - 512];
}

// ------- GroupNorm apply + transpose, vectorized: x fp32 -> hf bf16 [b][n][c]
__global__ __launch_bounds__(256) void gn_apply_k(const float* __restrict__ x,
                                                  const float* __restrict__ stats,
                                                  const float* __restrict__ gw,
                                                  const float* __restrict__ gb,
                                                  __hip_bfloat16* __restrict__ hf) {
  int c0 = blockIdx.x * 64, n0 = blockIdx.y * 64, b = blockIdx.z;
  __shared__ float tile[64][65];
  int tid = threadIdx.x;
  int cl = tid >> 2, q = tid & 3;
  int c = c0 + cl;
  float mean = stats[(b * 32 + (c >> 4)) * 2];
  float rstd = stats[(b * 32 + (c >> 4)) * 2 + 1];
  float sc = rstd * gw[c];
  float sh = gb[c] - mean * sc;
  const float* xr = x + ((size_t)(b * 512 + c0 + cl)) * 4096 + n0 + q * 16;
#pragma unroll
  for (int j = 0; j < 4; j++) {
    float4 v = *(const float4*)(xr + 4 * j);
    int n = q * 16 + 4 * j;
    tile[cl][n]     = v.x * sc + sh;
    tile[cl][n + 1] = v.y * sc + sh;
    tile[cl][n + 2] = v.z * sc + sh;
    tile[cl][n + 3] = v.w * sc + sh;
  }
  __syncthreads();
  int nl = tid >> 2, ch = q * 16;
  bf16x8 o0, o1;
#pragma unroll
  for (int l = 0; l < 8; l++) {
    o0[l] = (__bf16)tile[ch + l][nl];
    o1[l] = (__bf16)tile[ch + 8 + l][nl];
  }
  __hip_bfloat16* op = hf + ((size_t)(b * 4096 + n0 + nl)) * 512 + c0 + ch;
  *(uint4*)op = *(uint4*)&o0;
  *(uint4*)(op + 8) = *(uint4*)&o1;
}

// ============ fused QKV (double-buffered DMA + LDS epilogue) ============
// bx<8 : QK GEMM  qk[t][o] (o<1024) = sum_c hf[t][c]*Wqk[o][c] + bqk[o]
// bx>=8: V GEMM   vT[b][o][t]       = sum_c Wv[o][c]*hf[t][c] + bv[o]
__global__ __launch_bounds__(256, 4) void qkv_k(
    const __hip_bfloat16* __restrict__ hf, const __hip_bfloat16* __restrict__ wqk,
    const __hip_bfloat16* __restrict__ wv, const float* __restrict__ bqk,
    const float* __restrict__ bv, __hip_bfloat16* __restrict__ qk,
    __hip_bfloat16* __restrict__ vT) {
  bool isV = blockIdx.x >= 8;
  int m0 = isV ? (blockIdx.x - 8) * 128 : blockIdx.y * 128;
  int n0 = isV ? blockIdx.y * 128 : blockIdx.x * 128;
  const __hip_bfloat16* A  = isV ? wv : hf;   // [m][512]
  const __hip_bfloat16* Bm = isV ? hf : wqk;  // [n][512]

  __shared__ __align__(16) unsigned char smem[34816];  // dbuf(32K) | epi(34K)
  __hip_bfloat16* As  = (__hip_bfloat16*)smem;
  __hip_bfloat16* Bs  = As + 8192;
  __hip_bfloat16* epi = (__hip_bfloat16*)smem;         // [128][136]

  int tid  = threadIdx.x;
  int wvx  = tid >> 6, lane = tid & 63;
  int wr   = (wvx >> 1) * 64, wc = (wvx & 1) * 64;
  int quad = lane >> 4, l16 = lane & 15;

  int srow = wvx * 32 + (lane >> 2);
  int scol = (lane & 3) * 8;
  const __hip_bfloat16* gA0 = A  + (size_t)(m0 + srow) * 512 + scol;
  const __hip_bfloat16* gA1 = gA0 + (size_t)16 * 512;
  const __hip_bfloat16* gB0 = Bm + (size_t)(n0 + srow) * 512 + scol;
  const __hip_bfloat16* gB1 = gB0 + (size_t)16 * 512;

  auto stage = [&](int kk, int bsel) {
    int lb = bsel * 4096 + wvx * 1024;
    gload_lds16(gA0 + kk, &As[lb]);
    gload_lds16(gA1 + kk, &As[lb + 512]);
    gload_lds16(gB0 + kk, &Bs[lb]);
    gload_lds16(gB1 + kk, &Bs[lb + 512]);
  };

  f32x4 acc[4][4] = {};
  stage(0, 0);
  for (int kt = 0; kt < 16; kt++) {
    __syncthreads();
    if (kt + 1 < 16) stage((kt + 1) << 5, (kt + 1) & 1);
    const __hip_bfloat16* Ab = &As[(kt & 1) * 4096];
    const __hip_bfloat16* Bb = &Bs[(kt & 1) * 4096];
    bf16x8 af[4], bfr[4];
#pragma unroll
    for (int i = 0; i < 4; i++)
      af[i] = *(const bf16x8*)&Ab[(wr + i * 16 + l16) * 32 + quad * 8];
#pragma unroll
    for (int j = 0; j < 4; j++)
      bfr[j] = *(const bf16x8*)&Bb[(wc + j * 16 + l16) * 32 + quad * 8];
#pragma unroll
    for (int i = 0; i < 4; i++)
#pragma unroll
      for (int j = 0; j < 4; j++)
        acc[i][j] = __builtin_amdgcn_mfma_f32_16x16x32_bf16(af[i], bfr[j],
                                                            acc[i][j], 0, 0, 0);
  }

  // ---- epilogue via LDS: C-layout -> row-major coalesced ----
  float bj[4], bm[4][4];
  if (!isV) {
#pragma unroll
    for (int j = 0; j < 4; j++) bj[j] = bqk[n0 + wc + j * 16 + l16];
  } else {
#pragma unroll
    for (int i = 0; i < 4; i++)
#pragma unroll
      for (int r = 0; r < 4; r++)
        bm[i][r] = bv[m0 + wr + i * 16 + quad * 4 + r];
  }
  __syncthreads();  // dbuf fragment reads done before epi overwrite
#pragma unroll
  for (int i = 0; i < 4; i++)
#pragma unroll
    for (int j = 0; j < 4; j++)
#pragma unroll
      for (int r = 0; r < 4; r++) {
        int ml = wr + i * 16 + quad * 4 + r;
        int nl = wc + j * 16 + l16;
        float v = acc[i][j][r] + (isV ? bm[i][r] : bj[j]);
        epi[ml * 136 + nl] = __float2bfloat16(v);
      }
  __syncthreads();
  int mr = tid >> 1, h = tid & 1;
  const __hip_bfloat16* rowp = &epi[mr * 136 + h * 64];
  if (!isV) {
    __hip_bfloat16* o = qk + (size_t)(m0 + mr) * 1024 + n0 + h * 64;
#pragma unroll
    for (int c = 0; c < 8; c++)
      *(uint4*)(o + c * 8) = *(const uint4*)(rowp + c * 8);
  } else {
    int b = (n0 + h * 64) >> 12, t = (n0 + h * 64) & 4095;
    __hip_bfloat16* o = vT + ((size_t)(b * 512 + m0 + mr)) * 4096 + t;
#pragma unroll
    for (int c = 0; c < 8; c++)
      *(uint4*)(o + c * 8) = *(const uint4*)(rowp + c * 8);
  }
}

// ------------- QK^T GEMM: expS + atomic-free row sums -------
__global__ __launch_bounds__(256, 4) void qkexp_k(
    const __hip_bfloat16* __restrict__ A, const __hip_bfloat16* __restrict__ Bm,
    __hip_bfloat16* __restrict__ Cout, float* __restrict__ psums) {
  int bx = blockIdx.x, by = blockIdx.y, bb = blockIdx.z;
  const float scale = 0.044194173824159216f;
  A  += (size_t)bb * 4096 * 1024;
  Bm += (size_t)bb * 4096 * 1024 + 512;
  size_t cbase = (size_t)bb * 4096 * 4096;
  int m0 = by * 128, n0 = bx * 128;

  __shared__ __align__(16) unsigned char smem[33792];  // dbuf(32K) | psum2(1K)
  __hip_bfloat16* As  = (__hip_bfloat16*)smem;
  __hip_bfloat16* Bs  = As + 8192;
  float* psum2 = (float*)(smem + 32768);               // [2][128]

  int tid  = threadIdx.x;
  int wv   = tid >> 6, lane = tid & 63;
  int wr   = (wv >> 1) * 64, wc = (wv & 1) * 64;
  int quad = lane >> 4, l16 = lane & 15;

  int srow = wv * 32 + (lane >> 2);
  int scol = (lane & 3) * 8;
  const __hip_bfloat16* gA0 = A  + (size_t)(m0 + srow) * 1024 + scol;
  const __hip_bfloat16* gA1 = gA0 + (size_t)16 * 1024;
  const __hip_bfloat16* gB0 = Bm + (size_t)(n0 + srow) * 1024 + scol;
  const __hip_bfloat16* gB1 = gB0 + (size_t)16 * 1024;

  auto stage = [&](int kk, int bsel) {
    int lb = bsel * 4096 + wv * 1024;
    gload_lds16(gA0 + kk, &As[lb]);
    gload_lds16(gA1 + kk, &As[lb + 512]);
    gload_lds16(gB0 + kk, &Bs[lb]);
    gload_lds16(gB1 + kk, &Bs[lb + 512]);
  };

  f32x4 acc[4][4] = {};
  stage(0, 0);
  for (int kt = 0; kt < 16; kt++) {
    __syncthreads();
    if (kt + 1 < 16) stage((kt + 1) << 5, (kt + 1) & 1);
    const __hip_bfloat16* Ab = &As[(kt & 1) * 4096];
    const __hip_bfloat16* Bb = &Bs[(kt & 1) * 4096];
    bf16x8 af[4], bfr[4];
#pragma unroll
    for (int i = 0; i < 4; i++)
      af[i] = *(const bf16x8*)&Ab[(wr + i * 16 + l16) * 32 + quad * 8];
#pragma unroll
    for (int j = 0; j < 4; j++)
      bfr[j] = *(const bf16x8*)&Bb[(wc + j * 16 + l16) * 32 + quad * 8];
#pragma unroll
    for (int i = 0; i < 4; i++)
#pragma unroll
      for (int j = 0; j < 4; j++)
        acc[i][j] = __builtin_amdgcn_mfma_f32_16x16x32_bf16(af[i], bfr[j],
                                                            acc[i][j], 0, 0, 0);
  }

  // direct scattered stores, row-contiguous order (i,r outer; j inner so the
  // four 32B segments of each 128B row-span issue back-to-back)
  float s[4][4];
#pragma unroll
  for (int i = 0; i < 4; i++)
#pragma unroll
    for (int r = 0; r < 4; r++) s[i][r] = 0.f;
#pragma unroll
  for (int i = 0; i < 4; i++)
#pragma unroll
    for (int r = 0; r < 4; r++) {
      int m = m0 + wr + i * 16 + quad * 4 + r;
      size_t rb = cbase + (size_t)m * 4096 + n0;
#pragma unroll
      for (int j = 0; j < 4; j++) {
        float v = __expf(acc[i][j][r] * scale);
        Cout[rb + wc + j * 16 + l16] = __float2bfloat16(v);
        s[i][r] += v;
      }
    }
#pragma unroll
  for (int off = 1; off < 16; off <<= 1)
#pragma unroll
    for (int i = 0; i < 4; i++)
#pragma unroll
      for (int r = 0; r < 4; r++) s[i][r] += __shfl_xor(s[i][r], off);
  if (l16 == 0) {
#pragma unroll
    for (int i = 0; i < 4; i++)
#pragma unroll
      for (int r = 0; r < 4; r++)
        psum2[(wv & 1) * 128 + wr + i * 16 + quad * 4 + r] = s[i][r];
  }
  __syncthreads();
  if (tid < 128)
    psums[(size_t)bx * 8192 + bb * 4096 + m0 + tid] =
        psum2[tid] + psum2[128 + tid];
}

// ---- fold 32 per-n-tile row-sum partials into rowsumf[8192] ----
__global__ __launch_bounds__(256) void sum32_k(const float* __restrict__ psums,
                                               float* __restrict__ rowsumf) {
  int i = blockIdx.x * 256 + threadIdx.x;  // 0..8191
  float s = 0.f;
#pragma unroll
  for (int j = 0; j < 32; j++) s += psums[(size_t)j * 8192 + i];
  rowsumf[i] = s;
}

// ============ PV split-K: BK=64 staging, XOR-swizzled LDS ============
// part[bz][m][c] = sum_{k in ks half} expS[bb][m][k] * vT[bb][c][k]
__global__ __launch_bounds__(256, 2) void pv_k(
    const __hip_bfloat16* __restrict__ P, const __hip_bfloat16* __restrict__ vT,
    __hip_bfloat16* __restrict__ part) {
  // 512 blocks; co-locate the 4 c-tiles of each (m,bz) group on one XCD
  int f = blockIdx.x;
  int xcd = f & 7, s = f >> 3;
  int bx = s & 3;
  int g = xcd + 8 * (s >> 2);     // 0..127
  int by = g & 31, bz = g >> 5;   // bz = bb*2+ks
  int bb = bz >> 1, ks = bz & 1;
  const __hip_bfloat16* A = P  + (size_t)bb * 4096 * 4096 + (size_t)ks * 2048;
  const __hip_bfloat16* B = vT + (size_t)bb * 512 * 4096 + (size_t)ks * 2048;
  size_t cbase = (size_t)bz * 4096 * 512;
  int m0 = by * 128, n0 = bx * 128;

  __shared__ __align__(16) unsigned char smem[65536];  // dbuf 64K; epi overlaps
  __hip_bfloat16* As  = (__hip_bfloat16*)smem;          // 2 x [128][64]
  __hip_bfloat16* Bs  = (__hip_bfloat16*)(smem + 32768);
  __hip_bfloat16* epi = (__hip_bfloat16*)smem;          // [128][136]

  int tid = threadIdx.x, wv = tid >> 6, lane = tid & 63;
  int wr = (wv >> 1) * 64, wc = (wv & 1) * 64;
  int quad = lane >> 4, l16 = lane & 15;

  // DMA: inst covers 8 rows x 128B; lane l -> row l>>3, swizzled chunk
  // (l&7)^(l>>3). LDS[r][x] = G[r][x ^ (r&7)] so b128 frag reads are 2-way.
  int srow = wv * 32 + (lane >> 3);
  int scol = ((lane & 7) ^ (lane >> 3)) * 8;
  const __hip_bfloat16* gA = A + (size_t)(m0 + srow) * 4096 + scol;
  const __hip_bfloat16* gB = B + (size_t)(n0 + srow) * 4096 + scol;

  auto stage = [&](int kk, int bsel) {
    __hip_bfloat16* la = &As[bsel * 8192 + wv * 2048];
    __hip_bfloat16* lb = &Bs[bsel * 8192 + wv * 2048];
#pragma unroll
    for (int c = 0; c < 4; c++) {
      gload_lds16(gA + kk + (size_t)(c * 8) * 4096, la + c * 512);
      gload_lds16(gB + kk + (size_t)(c * 8) * 4096, lb + c * 512);
    }
  };

  f32x4 acc[4][4] = {};
  stage(0, 0);
  for (int kt = 0; kt < 32; kt++) {
    __syncthreads();
    if (kt + 1 < 32) stage((kt + 1) << 6, (kt + 1) & 1);
    const __hip_bfloat16* Ab = &As[(kt & 1) * 8192];
    const __hip_bfloat16* Bb = &Bs[(kt & 1) * 8192];
#pragma unroll
    for (int ksub = 0; ksub < 2; ksub++) {
      bf16x8 af[4], bfr[4];
#pragma unroll
      for (int i = 0; i < 4; i++) {
        int r = wr + i * 16 + l16;
        af[i] = *(const bf16x8*)&Ab[r * 64 + ((ksub * 4 + quad) ^ (r & 7)) * 8];
      }
#pragma unroll
      for (int j = 0; j < 4; j++) {
        int r = wc + j * 16 + l16;
        bfr[j] = *(const bf16x8*)&Bb[r * 64 + ((ksub * 4 + quad) ^ (r & 7)) * 8];
      }
#pragma unroll
      for (int i = 0; i < 4; i++)
#pragma unroll
        for (int j = 0; j < 4; j++)
          acc[i][j] = __builtin_amdgcn_mfma_f32_16x16x32_bf16(af[i], bfr[j],
                                                              acc[i][j], 0, 0, 0);
    }
  }

  __syncthreads();
#pragma unroll
  for (int i = 0; i < 4; i++)
#pragma unroll
    for (int j = 0; j < 4; j++)
#pragma unroll
      for (int r = 0; r < 4; r++)
        epi[(wr + i * 16 + quad * 4 + r) * 136 + wc + j * 16 + l16] =
            __float2bfloat16(acc[i][j][r]);
  __syncthreads();
  int mr = tid >> 1, h = tid & 1;
  const __hip_bfloat16* rowp = &epi[mr * 136 + h * 64];
  __hip_bfloat16* o = part + cbase + (size_t)(m0 + mr) * 512 + n0 + h * 64;
#pragma unroll
  for (int c = 0; c < 8; c++)
    *(uint4*)(o + c * 8) = *(const uint4*)(rowp + c * 8);
}

// ====== fused out-proj + split-K reduce + normalize, 64x128 tiles ======
// out[b][c][t] = x + bf16( inv[t] * sum_o Wo[c][o]*(part0+part1)[t][o] + bo[c] )
__global__ __launch_bounds__(256, 2) void oproj_k(
    const __hip_bfloat16* __restrict__ Wo, const __hip_bfloat16* __restrict__ part,
    float* __restrict__ out, const float* __restrict__ bias,
    const float* __restrict__ resid, const float* __restrict__ rowsumf) {
  int m0 = blockIdx.y * 64, n0 = blockIdx.x * 128, bb = blockIdx.z;
  const __hip_bfloat16* P0 = part + (size_t)(bb * 2) * 4096 * 512;
  const __hip_bfloat16* P1 = P0 + (size_t)4096 * 512;
  size_t cbase = (size_t)bb * 512 * 4096;

  __shared__ __align__(16) unsigned char smem[40960];  // A 2x4K | B0,B1 2x8K
  __hip_bfloat16* As  = (__hip_bfloat16*)smem;          // 2 x [64][32]
  __hip_bfloat16* B0s = As + 4096;                      // 2 x [128][32]
  __hip_bfloat16* B1s = B0s + 8192;                     // 2 x [128][32]
  __hip_bfloat16* epi = (__hip_bfloat16*)smem;          // [64][136] = 17.4K

  int tid = threadIdx.x, wv = tid >> 6, lane = tid & 63;
  int wr = (wv >> 1) * 32, wc = (wv & 1) * 64;
  int quad = lane >> 4, l16 = lane & 15;

  int lr = lane >> 2, scol = (lane & 3) * 8;
  const __hip_bfloat16* gA   = Wo + (size_t)(m0 + wv * 16 + lr) * 512 + scol;
  const __hip_bfloat16* gB0a = P0 + (size_t)(n0 + wv * 32 + lr) * 512 + scol;
  const __hip_bfloat16* gB0b = gB0a + (size_t)16 * 512;
  const __hip_bfloat16* gB1a = P1 + (size_t)(n0 + wv * 32 + lr) * 512 + scol;
  const __hip_bfloat16* gB1b = gB1a + (size_t)16 * 512;

  auto stage = [&](int kk, int bsel) {
    gload_lds16(gA + kk,   &As[bsel * 2048 + wv * 512]);
    gload_lds16(gB0a + kk, &B0s[bsel * 4096 + wv * 1024]);
    gload_lds16(gB0b + kk, &B0s[bsel * 4096 + wv * 1024 + 512]);
    gload_lds16(gB1a + kk, &B1s[bsel * 4096 + wv * 1024]);
    gload_lds16(gB1b + kk, &B1s[bsel * 4096 + wv * 1024 + 512]);
  };

  f32x4 acc[2][4] = {};
  stage(0, 0);
  for (int kt = 0; kt < 16; kt++) {
    __syncthreads();
    if (kt + 1 < 16) stage((kt + 1) << 5, (kt + 1) & 1);
    const __hip_bfloat16* Ab  = &As[(kt & 1) * 2048];
    const __hip_bfloat16* Bb0 = &B0s[(kt & 1) * 4096];
    const __hip_bfloat16* Bb1 = &B1s[(kt & 1) * 4096];
    bf16x8 af[2], b0[4], b1[4];
#pragma unroll
    for (int i = 0; i < 2; i++)
      af[i] = *(const bf16x8*)&Ab[(wr + i * 16 + l16) * 32 + quad * 8];
#pragma unroll
    for (int j = 0; j < 4; j++) {
      b0[j] = *(const bf16x8*)&Bb0[(wc + j * 16 + l16) * 32 + quad * 8];
      b1[j] = *(const bf16x8*)&Bb1[(wc + j * 16 + l16) * 32 + quad * 8];
    }
#pragma unroll
    for (int i = 0; i < 2; i++)
#pragma unroll
      for (int j = 0; j < 4; j++) {
        acc[i][j] = __builtin_amdgcn_mfma_f32_16x16x32_bf16(af[i], b0[j],
                                                            acc[i][j], 0, 0, 0);
        acc[i][j] = __builtin_amdgcn_mfma_f32_16x16x32_bf16(af[i], b1[j],
                                                            acc[i][j], 0, 0, 0);
      }
  }

  float pre[2][4], invj[4];
#pragma unroll
  for (int i = 0; i < 2; i++)
#pragma unroll
    for (int r = 0; r < 4; r++)
      pre[i][r] = bias[m0 + wr + i * 16 + quad * 4 + r];
#pragma unroll
  for (int j = 0; j < 4; j++)
    invj[j] = 1.f / rowsumf[bb * 4096 + n0 + wc + j * 16 + l16];
  __syncthreads();
#pragma unroll
  for (int i = 0; i < 2; i++)
#pragma unroll
    for (int j = 0; j < 4; j++)
#pragma unroll
      for (int r = 0; r < 4; r++)
        epi[(wr + i * 16 + quad * 4 + r) * 136 + wc + j * 16 + l16] =
            __float2bfloat16(acc[i][j][r] * invj[j] + pre[i][r]);
  __syncthreads();
  int mr = tid >> 2, seg = tid & 3;  // 4 threads/row, 32 elems each
  const __hip_bfloat16* rowp = &epi[mr * 136 + seg * 32];
  size_t obase = cbase + (size_t)(m0 + mr) * 4096 + n0 + seg * 32;
#pragma unroll
  for (int c = 0; c < 4; c++) {
    bf16x8 val = *(const bf16x8*)(rowp + c * 8);
    size_t idx = obase + c * 8;
    float4 r0 = *(const float4*)&resid[idx];
    float4 r1 = *(const float4*)&resid[idx + 4];
    float4 o0, o1;
    o0.x = r0.x + (float)val[0]; o0.y = r0.y + (float)val[1];
    o0.z = r0.z + (float)val[2]; o0.w = r0.w + (float)val[3];
    o1.x = r1.x + (float)val[4]; o1.y = r1.y + (float)val[5];
    o1.z = r1.z + (float)val[6]; o1.w = r1.w + (float)val[7];
    *(float4*)&out[idx] = o0;
    *(float4*)&out[idx + 4] = o1;
  }
}

extern "C" void kernel_launch(void* const* d_in, const int* in_sizes, int n_in,
                              void* d_out, int out_size, void* d_ws,
                              size_t ws_size, hipStream_t stream) {
  const float* xp  = (const float*)d_in[0];
  const float* gwp = (const float*)d_in[1];
  const float* gbp = (const float*)d_in[2];
  const float* wqp = (const float*)d_in[3];
  const float* bqp = (const float*)d_in[4];
  const float* wkp = (const float*)d_in[5];
  const float* bkp = (const float*)d_in[6];
  const float* wvp = (const float*)d_in[7];
  const float* bvp = (const float*)d_in[8];
  const float* wop = (const float*)d_in[9];
  const float* bop = (const float*)d_in[10];
  float* outp = (float*)d_out;

  char* w = (char*)d_ws;
  size_t off = 0;
  auto alloc = [&](size_t bytes) {
    void* p = w + off;
    off += (bytes + 255) & ~(size_t)255;
    return p;
  };
  float* stats         = (float*)alloc(64 * 2 * sizeof(float));
  __hip_bfloat16* hf   = (__hip_bfloat16*)alloc((size_t)2 * 4096 * 512 * 2);
  __hip_bfloat16* wqkb = (__hip_bfloat16*)alloc((size_t)1024 * 512 * 2);
  __hip_bfloat16* wvb  = (__hip_bfloat16*)alloc((size_t)512 * 512 * 2);
  __hip_bfloat16* wob  = (__hip_bfloat16*)alloc((size_t)512 * 512 * 2);
  float* bqk           = (float*)alloc(1024 * sizeof(float));
  float* psums         = (float*)alloc((size_t)32 * 8192 * sizeof(float));
  float* rowsumf       = (float*)alloc(8192 * sizeof(float));
  __hip_bfloat16* qk   = (__hip_bfloat16*)alloc((size_t)2 * 4096 * 1024 * 2);
  __hip_bfloat16* vT   = (__hip_bfloat16*)alloc((size_t)2 * 512 * 4096 * 2);
  __hip_bfloat16* part = (__hip_bfloat16*)alloc((size_t)4 * 4096 * 512 * 2);
  __hip_bfloat16* Sbuf = (__hip_bfloat16*)alloc((size_t)2 * 4096 * 4096 * 2);

  // prelude: 4096 cvt blocks + 64 gn_stats blocks + 1 bcat block
  prelude_k<<<4161, 256, 0, stream>>>(wqp, wkp, wvp, wop, wqkb, wvb, wob,
                                      bqp, bkp, bqk, xp, stats);

  gn_apply_k<<<dim3(8, 64, 2), 256, 0, stream>>>(xp, stats, gwp, gbp, hf);

  // fused QKV: qk[8192][1024] and vT[2][512][4096]
  qkv_k<<<dim3(12, 64, 1), 256, 0, stream>>>(hf, wqkb, wvb, bqk, bvp, qk, vT);

  // expS = exp(Q K^T * scale), both batches (bf16) + per-n-tile row sums
  qkexp_k<<<dim3(32, 32, 2), 256, 0, stream>>>(qk, qk, Sbuf, psums);

  // fold 32 partial sums -> rowsumf[8192]
  sum32_k<<<32, 256, 0, stream>>>(psums, rowsumf);

  // PV split-K (kspl=2, BK=64, XCD-swizzled): raw partials [4][4096][512]
  pv_k<<<512, 256, 0, stream>>>(Sbuf, vT, part);

  // fused: out[b][c][t] = x + inv[t]*(Wo*(part0+part1)) + bo
  oproj_k<<<dim3(32, 8, 2), 256, 0, stream>>>(wob, part, outp, bop, xp,
                                              rowsumf);
}